// Round 4
// baseline (774.995 us; speedup 1.0000x reference)
//
#include <hip/hip_runtime.h>
#include <math.h>

// Problem constants (fixed by the reference)
#define BB 128
#define NN 2048
#define HH 300
#define EE 20
#define MM 200
#define NEGV (-10000.0f)
#define SCORES_OFF (BB * (NN + 1))   // new_mem starts here in d_out

// B-image geometry (LDS-ready layout, built by k_prep, streamed by k_main)
#define NCOL 208                     // 200 cols padded to 13*16
#define KSTEPS 10                    // K: 300 padded to 320 = 10*32
#define ROWSH 72                     // shorts per col: hi[32] | lo[32] | pad[8] = 144 B
#define KIMG (NCOL * ROWSH)          // shorts per (b,kstep) image = 14976 (29952 B)
#define BIMG_SHORTS ((size_t)BB * KSTEPS * KIMG)
#define FWS_FLOATS (BB * MM + 10 * MM + 10 * MM + BB * HH)  // bias|distW|cntW|avg

typedef short bf16x8 __attribute__((ext_vector_type(8)));
typedef float f32x4 __attribute__((ext_vector_type(4)));

// ---------------------------------------------------------------------------
// bucket: x<=4 -> x ; else floor(log(x)/log2)+3, clipped to [0,9]
// logf -> __ocml_log_f32, same float path the reference's jnp.log/LOG2 takes.
// ---------------------------------------------------------------------------
__device__ __forceinline__ int bucketf(int x) {
  if (x <= 4) return x < 0 ? 0 : x;
  float l = floorf(logf((float)x) / 0.69314718055994530942f);
  int bi = (int)l + 3;
  return bi > 9 ? 9 : bi;
}

// float -> bf16 (RNE) and back, bit ops
__device__ __forceinline__ short f2bf(float f) {
  union { float f; unsigned u; } v; v.f = f;
  unsigned r = (v.u + 0x7FFFu + ((v.u >> 16) & 1u)) >> 16;
  return (short)r;
}
__device__ __forceinline__ float bf2f(short s) {
  union { unsigned u; float f; } v; v.u = ((unsigned)(unsigned short)s) << 16;
  return v.f;
}

// ---------------------------------------------------------------------------
// k_small: fused tiny prep. Blocks [0,13): tables; [13,93): bias; [93,221): avg.
//   tables: distW[d][m] = sum_e dtab[d][e]*W1[3H+e][m]; cntW likewise at 3H+E.
//   bias:   bias[b][m] = b1[m] + sum_h q[b,h]*W1[H+h][m] + sum_e atab[la,e]*W1[3H+2E+e][m]
//   avg:    avg[b][h] = (mem[b,cell,h]*cnt + q[b,h])/(cnt+1); zero score col N.
// ---------------------------------------------------------------------------
__global__ void k_small(const float* __restrict__ W1, const float* __restrict__ b1,
                        const float* __restrict__ q, const float* __restrict__ mem,
                        const float* __restrict__ dtab, const float* __restrict__ ctab,
                        const float* __restrict__ atab, const int* __restrict__ lact,
                        const int* __restrict__ entc, const int* __restrict__ cell,
                        float* __restrict__ distW, float* __restrict__ cntW,
                        float* __restrict__ bias, float* __restrict__ avg,
                        float* __restrict__ out) {
  const int blk = blockIdx.x;
  const int tid = threadIdx.x;
  if (blk < 13) {                       // ---- tables: 2*10*200 = 4000 items
    int idx = blk * 320 + tid;
    if (idx >= 2 * 10 * MM) return;
    int t = idx / (10 * MM);
    int r = idx % (10 * MM);
    int d = r / MM;
    int m = r % MM;
    const float* tab = (t == 0) ? dtab : ctab;
    int wrow0 = (t == 0) ? (3 * HH) : (3 * HH + EE);
    float s = 0.f;
#pragma unroll
    for (int e = 0; e < EE; e++) s += tab[d * EE + e] * W1[(wrow0 + e) * MM + m];
    ((t == 0) ? distW : cntW)[d * MM + m] = s;
  } else if (blk < 93) {                // ---- bias: 128*200 = 25600 items
    int idx = (blk - 13) * 320 + tid;
    if (idx >= BB * MM) return;
    int b = idx / MM;
    int m = idx % MM;
    float s = b1[m];
    for (int h = 0; h < HH; h++) s += q[b * HH + h] * W1[(HH + h) * MM + m];
    int la = lact[b];
#pragma unroll
    for (int e = 0; e < EE; e++)
      s += atab[la * EE + e] * W1[(3 * HH + 2 * EE + e) * MM + m];
    bias[idx] = s;
  } else {                              // ---- avg: 128 batches
    int b = blk - 93;
    int ci = cell[b];
    if (tid < HH) {
      float c = (float)entc[b * NN + ci];
      float m = mem[((size_t)b * NN + ci) * HH + tid];
      avg[b * HH + tid] = (m * c + q[b * HH + tid]) / (c + 1.f);
    } else if (tid == HH) {
      out[b * (NN + 1) + NN] = 0.f;
    }
  }
}

// ---------------------------------------------------------------------------
// k_prep: Bimg[b][ks][col] = {hi bf16 x32 | lo bf16 x32 | pad x8} for
//   W1eff^T[k, col] = W1[k][col] + q[b][k]*W1[2H+k][col],  k = ks*32 + 8g + i.
// One thread per (b,ks,col): writes 144 B contiguous (fully coalesced).
// ---------------------------------------------------------------------------
__global__ void k_prep(const float* __restrict__ W1, const float* __restrict__ q,
                       short* __restrict__ Bimg) {
  int idx = blockIdx.x * blockDim.x + threadIdx.x;   // (b*10+ks)*208+col
  if (idx >= BB * KSTEPS * NCOL) return;
  int col = idx % NCOL;
  int bks = idx / NCOL;
  int ks = bks % KSTEPS;
  int b = bks / KSTEPS;
  int k0 = ks * 32;
  const float* qb = q + b * HH;

  __align__(16) short buf[ROWSH];
#pragma unroll
  for (int g = 0; g < 4; g++) {
#pragma unroll
    for (int i = 0; i < 8; i++) {
      int k = k0 + 8 * g + i;
      float val = 0.f;
      if (k < HH && col < MM) {
        val = fmaf(qb[k], W1[(size_t)(2 * HH + k) * MM + col],
                   W1[(size_t)k * MM + col]);
      }
      short h = f2bf(val);
      buf[g * 8 + i] = h;
      buf[32 + g * 8 + i] = f2bf(val - bf2f(h));
    }
  }
#pragma unroll
  for (int i = 64; i < 72; i++) buf[i] = 0;

  float4* dst = (float4*)(Bimg + (size_t)idx * ROWSH);
  const float4* src = (const float4*)buf;
#pragma unroll
  for (int i = 0; i < 9; i++) dst[i] = src[i];
}

// ---------------------------------------------------------------------------
// Shared epilogue: + bias + distW/cntW rows, relu, dot W2, 16-lane reduce.
// C/D layout (m89): col = lane&15 -> m = f*16+lr ; row = 4g+reg -> n.
// ---------------------------------------------------------------------------
__device__ __forceinline__ void epilogue(
    const f32x4* acc, int b, int n0, int w, int lr, int g,
    const float* __restrict__ bias, const float* __restrict__ distW,
    const float* __restrict__ cntW, const float* __restrict__ W2,
    const float* __restrict__ b2, const float* __restrict__ ment,
    const int* __restrict__ entc, const int* __restrict__ dist,
    float* __restrict__ out) {
  const float addc = b2[0] + ment[b];
  const float* bi = bias + b * MM;
  float s[4];
#pragma unroll
  for (int r = 0; r < 4; r++) {
    int nr = n0 + w * 16 + 4 * g + r;
    int db = bucketf(dist[b * NN + nr]);
    int cb = bucketf(entc[b * NN + nr]);
    const float* dW = distW + db * MM;
    const float* cW = cntW + cb * MM;
    float acc_s = 0.f;
#pragma unroll
    for (int f = 0; f < 13; f++) {
      if (f < 12 || lr < 8) {  // m = f*16+lr < 200
        int m = f * 16 + lr;
        float h = acc[f][r] + bi[m] + dW[m] + cW[m];
        acc_s += fmaxf(h, 0.f) * W2[m];
      }
    }
    s[r] = acc_s;
  }
#pragma unroll
  for (int off = 1; off < 16; off <<= 1) {
#pragma unroll
    for (int r = 0; r < 4; r++) s[r] += __shfl_xor(s[r], off);
  }
  if (lr == 0) {
#pragma unroll
    for (int r = 0; r < 4; r++) {
      int nr = n0 + w * 16 + 4 * g + r;
      int mk = entc[b * NN + nr] > 0;
      out[b * (NN + 1) + nr] = mk ? (s[r] + addc) : NEGV;
    }
  }
}

// ---------------------------------------------------------------------------
// A-side: 8 fp32 from global + fused new_mem write + hi/lo bf16 split.
// ---------------------------------------------------------------------------
__device__ __forceinline__ void load_a(
    const float* rowp, float* orow, const float* avgp, bool subst, int kb,
    bf16x8* ahi, bf16x8* alo) {
  float va[8];
  if (kb + 7 < HH) {
    float4 x0 = *(const float4*)(rowp + kb);
    float4 x1 = *(const float4*)(rowp + kb + 4);
    va[0] = x0.x; va[1] = x0.y; va[2] = x0.z; va[3] = x0.w;
    va[4] = x1.x; va[5] = x1.y; va[6] = x1.z; va[7] = x1.w;
    float4 o0 = x0, o1 = x1;
    if (subst) {
      o0 = *(const float4*)(avgp + kb);
      o1 = *(const float4*)(avgp + kb + 4);
    }
    *(float4*)(orow + kb) = o0;
    *(float4*)(orow + kb + 4) = o1;
  } else {
#pragma unroll
    for (int i = 0; i < 8; i++) {
      int k = kb + i;
      bool ok = (k < HH);
      va[i] = ok ? rowp[k] : 0.f;
      if (ok) orow[k] = subst ? avgp[k] : va[i];
    }
  }
#pragma unroll
  for (int i = 0; i < 8; i++) {
    short h = f2bf(va[i]);
    (*ahi)[i] = h;
    (*alo)[i] = f2bf(va[i] - bf2f(h));
  }
}

// ---------------------------------------------------------------------------
// k_main (fast path): 1D grid 4096, bijective XCD swizzle pins all 32
//   row-tiles of a batch to one XCD (Bimg 300KB stays L2-resident).
//   Per block: (batch b, 64 rows) = 4 waves x 16 rows.
//   MFMA 16x16x32 bf16, fp32 via hi/lo split (3 products, lo*lo dropped).
//   A: global->reg direct + fused new_mem write. B: linear float4 copy
//   Bimg->LDS. 144B/col stride -> b128 quad (lr+g)&7 uniform: conflict-free.
// ---------------------------------------------------------------------------
__global__ __launch_bounds__(256, 3) void k_main(
    const float* __restrict__ mem, const short* __restrict__ Bimg,
    const float* __restrict__ bias, const float* __restrict__ distW,
    const float* __restrict__ cntW, const float* __restrict__ W2,
    const float* __restrict__ b2, const float* __restrict__ ment,
    const int* __restrict__ entc, const int* __restrict__ dist,
    const int* __restrict__ cell, const float* __restrict__ avg,
    float* __restrict__ out) {
  __shared__ __align__(16) short btS[KIMG];  // 29952 B

  const int tid = threadIdx.x;
  const int bid = blockIdx.x;
  const int b = (bid & 7) * 16 + (bid >> 8);   // XCD-pinned batch
  const int n0 = ((bid >> 3) & 31) * 64;

  const int w = tid >> 6;
  const int l = tid & 63;
  const int lr = l & 15;
  const int g = l >> 4;

  const int ci = cell[b];
  const int n = n0 + w * 16 + lr;
  const float* rowp = mem + ((size_t)b * NN + n) * HH;
  float* orow = out + SCORES_OFF + ((size_t)b * NN + n) * HH;
  const float* avgp = avg + b * HH;
  const bool subst = (n == ci);

  f32x4 acc[13];
#pragma unroll
  for (int f = 0; f < 13; f++) acc[f] = (f32x4){0.f, 0.f, 0.f, 0.f};

  for (int ks = 0; ks < KSTEPS; ks++) {
    bf16x8 ahi, alo;
    load_a(rowp, orow, avgp, subst, ks * 32 + 8 * g, &ahi, &alo);

    __syncthreads();  // prior iteration's btS reads complete
    {
      const float4* bsrc = (const float4*)(Bimg + (size_t)(b * KSTEPS + ks) * KIMG);
      float4* bdst = (float4*)btS;
      for (int i = tid; i < KIMG / 8; i += 256) bdst[i] = bsrc[i];
    }
    __syncthreads();

#pragma unroll
    for (int f = 0; f < 13; f++) {
      const short* bp = &btS[(f * 16 + lr) * ROWSH + g * 8];
      bf16x8 bhi = *(const bf16x8*)bp;
      bf16x8 blo = *(const bf16x8*)(bp + 32);
      acc[f] = __builtin_amdgcn_mfma_f32_16x16x32_bf16(ahi, bhi, acc[f], 0, 0, 0);
      acc[f] = __builtin_amdgcn_mfma_f32_16x16x32_bf16(alo, bhi, acc[f], 0, 0, 0);
      acc[f] = __builtin_amdgcn_mfma_f32_16x16x32_bf16(ahi, blo, acc[f], 0, 0, 0);
    }
  }

  epilogue(acc, b, n0, w, lr, g, bias, distW, cntW, W2, b2, ment, entc, dist, out);
}

// ---------------------------------------------------------------------------
// k_main_fb (fallback, ws too small for Bimg): identical math; B image built
//   in-block from W1 + q each kstep (Round-1 variant, 272KB ws only).
// ---------------------------------------------------------------------------
__global__ __launch_bounds__(256, 3) void k_main_fb(
    const float* __restrict__ mem, const float* __restrict__ W1,
    const float* __restrict__ q, const float* __restrict__ bias,
    const float* __restrict__ distW, const float* __restrict__ cntW,
    const float* __restrict__ W2, const float* __restrict__ b2,
    const float* __restrict__ ment, const int* __restrict__ entc,
    const int* __restrict__ dist, const int* __restrict__ cell,
    const float* __restrict__ avg, float* __restrict__ out) {
  __shared__ __align__(16) short btS[KIMG];  // 29952 B

  const int tid = threadIdx.x;
  const int b = blockIdx.y;
  const int n0 = blockIdx.x * 64;
  const int w = tid >> 6;
  const int l = tid & 63;
  const int lr = l & 15;
  const int g = l >> 4;

  const int ci = cell[b];
  const int n = n0 + w * 16 + lr;
  const float* rowp = mem + ((size_t)b * NN + n) * HH;
  float* orow = out + SCORES_OFF + ((size_t)b * NN + n) * HH;
  const float* avgp = avg + b * HH;
  const bool subst = (n == ci);
  const float* qb = q + b * HH;

  f32x4 acc[13];
#pragma unroll
  for (int f = 0; f < 13; f++) acc[f] = (f32x4){0.f, 0.f, 0.f, 0.f};

  for (int ks = 0; ks < KSTEPS; ks++) {
    const int k0 = ks * 32;
    bf16x8 ahi, alo;
    load_a(rowp, orow, avgp, subst, k0 + 8 * g, &ahi, &alo);

    __syncthreads();
    for (int it = 0; it < 4; it++) {   // 832 tasks = (col 0..207) x (g 0..3)
      int idx = tid + it * 256;
      if (idx < 832) {
        int col = idx % NCOL;
        int gg = idx / NCOL;
        int kbb = k0 + 8 * gg;
        bf16x8 h8, l8;
#pragma unroll
        for (int i = 0; i < 8; i++) {
          int k = kbb + i;
          float val = 0.f;
          if (k < HH && col < MM) {
            val = fmaf(qb[k], W1[(size_t)(2 * HH + k) * MM + col],
                       W1[(size_t)k * MM + col]);
          }
          short h = f2bf(val);
          h8[i] = h;
          l8[i] = f2bf(val - bf2f(h));
        }
        short* dst = &btS[col * ROWSH + gg * 8];
        *(bf16x8*)dst = h8;
        *(bf16x8*)(dst + 32) = l8;
      }
    }
    __syncthreads();

#pragma unroll
    for (int f = 0; f < 13; f++) {
      const short* bp = &btS[(f * 16 + lr) * ROWSH + g * 8];
      bf16x8 bhi = *(const bf16x8*)bp;
      bf16x8 blo = *(const bf16x8*)(bp + 32);
      acc[f] = __builtin_amdgcn_mfma_f32_16x16x32_bf16(ahi, bhi, acc[f], 0, 0, 0);
      acc[f] = __builtin_amdgcn_mfma_f32_16x16x32_bf16(alo, bhi, acc[f], 0, 0, 0);
      acc[f] = __builtin_amdgcn_mfma_f32_16x16x32_bf16(ahi, blo, acc[f], 0, 0, 0);
    }
  }

  epilogue(acc, b, n0, w, lr, g, bias, distW, cntW, W2, b2, ment, entc, dist, out);
}

// ---------------------------------------------------------------------------
extern "C" void kernel_launch(void* const* d_in, const int* in_sizes, int n_in,
                              void* d_out, int out_size, void* d_ws, size_t ws_size,
                              hipStream_t stream) {
  const float* q    = (const float*)d_in[0];
  const float* ment = (const float*)d_in[1];
  const float* mem  = (const float*)d_in[2];
  const int* entc   = (const int*)d_in[3];
  const int* dist   = (const int*)d_in[4];
  const int* lact   = (const int*)d_in[5];
  const int* cell   = (const int*)d_in[6];
  const float* W1   = (const float*)d_in[7];
  const float* b1   = (const float*)d_in[8];
  const float* W2   = (const float*)d_in[9];
  const float* b2   = (const float*)d_in[10];
  const float* dtab = (const float*)d_in[11];
  const float* ctab = (const float*)d_in[12];
  const float* atab = (const float*)d_in[13];
  float* out = (float*)d_out;

  const size_t need_fast = BIMG_SHORTS * sizeof(short) + FWS_FLOATS * sizeof(float);
  const bool fast = (ws_size >= need_fast);   // constant across calls: capture-safe

  short* Bimg = (short*)d_ws;
  float* fws  = fast ? (float*)(Bimg + BIMG_SHORTS) : (float*)d_ws;
  float* bias  = fws;
  float* distW = bias + BB * MM;
  float* cntW  = distW + 10 * MM;
  float* avg   = cntW + 10 * MM;

  k_small<<<221, 320, 0, stream>>>(W1, b1, q, mem, dtab, ctab, atab, lact,
                                   entc, cell, distW, cntW, bias, avg, out);
  if (fast) {
    k_prep<<<(BB * KSTEPS * NCOL) / 256, 256, 0, stream>>>(W1, q, Bimg);
    k_main<<<4096, 256, 0, stream>>>(mem, Bimg, bias, distW, cntW, W2, b2,
                                     ment, entc, dist, cell, avg, out);
  } else {
    k_main_fb<<<dim3(NN / 64, BB), 256, 0, stream>>>(
        mem, W1, q, bias, distW, cntW, W2, b2, ment, entc, dist, cell, avg, out);
  }
}

// Round 5
// 708.301 us; speedup vs baseline: 1.0942x; 1.0942x over previous
//
#include <hip/hip_runtime.h>
#include <math.h>

// Problem constants (fixed by the reference)
#define BB 128
#define NN 2048
#define HH 300
#define EE 20
#define MM 200
#define NEGV (-10000.0f)
#define SCORES_OFF (BB * (NN + 1))   // new_mem starts here in d_out

// B-image geometry (LDS-ready layout, built by k_prep2, streamed by k_main)
#define NCOL 208                     // 200 cols padded to 13*16
#define KSTEPS 10                    // K: 300 padded to 320 = 10*32
#define ROWSH 72                     // shorts per col: hi[32] | lo[32] | pad[8] = 144 B
#define KIMG (NCOL * ROWSH)          // shorts per (b,kstep) image = 14976 (29952 B)
#define CH16 (KIMG / 8)              // 1872 16-byte chunks per image
#define BIMG_SHORTS ((size_t)BB * KSTEPS * KIMG)

typedef short bf16x8 __attribute__((ext_vector_type(8)));
typedef float f32x4 __attribute__((ext_vector_type(4)));

// ---------------------------------------------------------------------------
// bucket: x<=4 -> x ; else floor(log(x)/log2)+3, clipped to [0,9]
// ---------------------------------------------------------------------------
__device__ __forceinline__ int bucketf(int x) {
  if (x <= 4) return x < 0 ? 0 : x;
  float l = floorf(logf((float)x) / 0.69314718055994530942f);
  int bi = (int)l + 3;
  return bi > 9 ? 9 : bi;
}

// float -> bf16 (RNE) and back, bit ops
__device__ __forceinline__ short f2bf(float f) {
  union { float f; unsigned u; } v; v.f = f;
  unsigned r = (v.u + 0x7FFFu + ((v.u >> 16) & 1u)) >> 16;
  return (short)r;
}
__device__ __forceinline__ float bf2f(short s) {
  union { unsigned u; float f; } v; v.u = ((unsigned)(unsigned short)s) << 16;
  return v.f;
}

// async global->LDS, 16B per lane (global_load_lds_dwordx4)
__device__ __forceinline__ void gload16(const void* g, void* l) {
  __builtin_amdgcn_global_load_lds(
      (const __attribute__((address_space(1))) void*)g,
      (__attribute__((address_space(3))) void*)l, 16, 0, 0);
}

// ---------------------------------------------------------------------------
// k_prep2: ONE dispatch for all prep. Block ranges:
//   [0,13): tables  distW[d][m], cntW[d][m]
//   [13,93): bias[b][m] = b1 + q.W1[H..2H) + actionEmb.W1[3H+2E..)
//   [93,221): avg[b][h] + zero score col N
//   [221,1053): Bimg build — direct bf16x8 stores, NO private array (scratch!)
// ---------------------------------------------------------------------------
__global__ void k_prep2(const float* __restrict__ W1, const float* __restrict__ b1,
                        const float* __restrict__ q, const float* __restrict__ mem,
                        const float* __restrict__ dtab, const float* __restrict__ ctab,
                        const float* __restrict__ atab, const int* __restrict__ lact,
                        const int* __restrict__ entc, const int* __restrict__ cell,
                        float* __restrict__ distW, float* __restrict__ cntW,
                        float* __restrict__ bias, float* __restrict__ avg,
                        short* __restrict__ Bimg, float* __restrict__ out) {
  const int blk = blockIdx.x;
  const int tid = threadIdx.x;
  if (blk < 13) {                       // ---- tables: 2*10*200 = 4000 items
    int idx = blk * 320 + tid;
    if (idx >= 2 * 10 * MM) return;
    int t = idx / (10 * MM);
    int r = idx % (10 * MM);
    int d = r / MM;
    int m = r % MM;
    const float* tab = (t == 0) ? dtab : ctab;
    int wrow0 = (t == 0) ? (3 * HH) : (3 * HH + EE);
    float s = 0.f;
#pragma unroll
    for (int e = 0; e < EE; e++) s += tab[d * EE + e] * W1[(wrow0 + e) * MM + m];
    ((t == 0) ? distW : cntW)[d * MM + m] = s;
  } else if (blk < 93) {                // ---- bias: 128*200 = 25600 items
    int idx = (blk - 13) * 320 + tid;
    if (idx >= BB * MM) return;
    int b = idx / MM;
    int m = idx % MM;
    float s = b1[m];
    for (int h = 0; h < HH; h++) s += q[b * HH + h] * W1[(HH + h) * MM + m];
    int la = lact[b];
#pragma unroll
    for (int e = 0; e < EE; e++)
      s += atab[la * EE + e] * W1[(3 * HH + 2 * EE + e) * MM + m];
    bias[idx] = s;
  } else if (blk < 221) {               // ---- avg: 128 batches
    int b = blk - 93;
    int ci = cell[b];
    if (tid < HH) {
      float c = (float)entc[b * NN + ci];
      float m = mem[((size_t)b * NN + ci) * HH + tid];
      avg[b * HH + tid] = (m * c + q[b * HH + tid]) / (c + 1.f);
    } else if (tid == HH) {
      out[b * (NN + 1) + NN] = 0.f;
    }
  } else {                              // ---- Bimg: 266240 items, exact fit
    int idx = (blk - 221) * 320 + tid;  // (b*10+ks)*208+col
    int col = idx % NCOL;
    int bks = idx / NCOL;
    int ks = bks % KSTEPS;
    int b = bks / KSTEPS;
    int k0 = ks * 32;
    const float* qb = q + b * HH;
    short* dst = Bimg + (size_t)idx * ROWSH;
#pragma unroll
    for (int g = 0; g < 4; g++) {
      bf16x8 h8, l8;
#pragma unroll
      for (int i = 0; i < 8; i++) {
        int k = k0 + 8 * g + i;
        float val = 0.f;
        if (k < HH && col < MM) {
          val = fmaf(qb[k], W1[(size_t)(2 * HH + k) * MM + col],
                     W1[(size_t)k * MM + col]);
        }
        short h = f2bf(val);
        h8[i] = h;
        l8[i] = f2bf(val - bf2f(h));
      }
      *(bf16x8*)(dst + g * 8) = h8;          // direct 16B stores from regs
      *(bf16x8*)(dst + 32 + g * 8) = l8;
    }
    *(bf16x8*)(dst + 64) = (bf16x8){0, 0, 0, 0, 0, 0, 0, 0};
  }
}

// ---------------------------------------------------------------------------
// A-side split: issue (loads only) / store new_mem / cvt to bf16 hi/lo.
// ---------------------------------------------------------------------------
__device__ __forceinline__ void issueA(const float* rowp, int kb, float* va) {
  if (kb + 7 < HH) {
    float4 x0 = *(const float4*)(rowp + kb);
    float4 x1 = *(const float4*)(rowp + kb + 4);
    va[0] = x0.x; va[1] = x0.y; va[2] = x0.z; va[3] = x0.w;
    va[4] = x1.x; va[5] = x1.y; va[6] = x1.z; va[7] = x1.w;
  } else {
#pragma unroll
    for (int i = 0; i < 8; i++) {
      int k = kb + i;
      va[i] = (k < HH) ? rowp[k] : 0.f;
    }
  }
}

__device__ __forceinline__ void storeA(const float* va, int kb, float* orow,
                                       const float* avgp, bool subst) {
  if (kb + 7 < HH) {
    float4 o0, o1;
    if (subst) {
      o0 = *(const float4*)(avgp + kb);
      o1 = *(const float4*)(avgp + kb + 4);
    } else {
      o0 = make_float4(va[0], va[1], va[2], va[3]);
      o1 = make_float4(va[4], va[5], va[6], va[7]);
    }
    *(float4*)(orow + kb) = o0;
    *(float4*)(orow + kb + 4) = o1;
  } else {
#pragma unroll
    for (int i = 0; i < 8; i++) {
      int k = kb + i;
      if (k < HH) orow[k] = subst ? avgp[k] : va[i];
    }
  }
}

__device__ __forceinline__ void cvtA(const float* va, bf16x8* ahi, bf16x8* alo) {
#pragma unroll
  for (int i = 0; i < 8; i++) {
    short h = f2bf(va[i]);
    (*ahi)[i] = h;
    (*alo)[i] = f2bf(va[i] - bf2f(h));
  }
}

// ---------------------------------------------------------------------------
// Epilogue: + bias + distW/cntW rows, relu, dot W2, 16-lane reduce.
// C/D layout (m89): col = lane&15 -> m = f*16+lr ; row = 4g+reg -> n.
// ---------------------------------------------------------------------------
__device__ __forceinline__ void epilogue(
    const f32x4* acc, int b, int n0, int w, int lr, int g,
    const float* __restrict__ bias, const float* __restrict__ distW,
    const float* __restrict__ cntW, const float* __restrict__ W2,
    const float* __restrict__ b2, const float* __restrict__ ment,
    const int* __restrict__ entc, const int* __restrict__ dist,
    float* __restrict__ out) {
  const float addc = b2[0] + ment[b];
  const float* bi = bias + b * MM;
  float s[4];
#pragma unroll
  for (int r = 0; r < 4; r++) {
    int nr = n0 + w * 16 + 4 * g + r;
    int db = bucketf(dist[b * NN + nr]);
    int cb = bucketf(entc[b * NN + nr]);
    const float* dW = distW + db * MM;
    const float* cW = cntW + cb * MM;
    float acc_s = 0.f;
#pragma unroll
    for (int f = 0; f < 13; f++) {
      if (f < 12 || lr < 8) {  // m = f*16+lr < 200
        int m = f * 16 + lr;
        float h = acc[f][r] + bi[m] + dW[m] + cW[m];
        acc_s += fmaxf(h, 0.f) * W2[m];
      }
    }
    s[r] = acc_s;
  }
#pragma unroll
  for (int off = 1; off < 16; off <<= 1) {
#pragma unroll
    for (int r = 0; r < 4; r++) s[r] += __shfl_xor(s[r], off);
  }
  if (lr == 0) {
#pragma unroll
    for (int r = 0; r < 4; r++) {
      int nr = n0 + w * 16 + 4 * g + r;
      int mk = entc[b * NN + nr] > 0;
      out[b * (NN + 1) + nr] = mk ? (s[r] + addc) : NEGV;
    }
  }
}

// ---------------------------------------------------------------------------
// k_main v3: 2048 blocks x 512 thr (8 waves, 128 rows/block).
//   Bijective XCD swizzle pins each batch's 16 tiles to one XCD.
//   Single barrier per kstep; LDS double-buffered (2x29952B).
//   B: global_load_lds (async, no VGPR round-trip), issued one kstep ahead
//      -> latency hidden under MFMA before the barrier drain.
//   A: issued one kstep ahead into regs; cvt after MFMA (latency window =
//      MFMA phase). new_mem stores issued at iter top (drain window = MFMA).
//   MFMA 16x16x32 bf16, fp32 via hi/lo split (3 products) - numerics
//   bit-identical to Round-4 PASS.
// ---------------------------------------------------------------------------
__global__ __launch_bounds__(512, 4) void k_main(
    const float* __restrict__ mem, const short* __restrict__ Bimg,
    const float* __restrict__ bias, const float* __restrict__ distW,
    const float* __restrict__ cntW, const float* __restrict__ W2,
    const float* __restrict__ b2, const float* __restrict__ ment,
    const int* __restrict__ entc, const int* __restrict__ dist,
    const int* __restrict__ cell, const float* __restrict__ avg,
    float* __restrict__ out) {
  __shared__ __align__(16) short btS[2][KIMG];  // 59904 B

  const int tid = threadIdx.x;
  const int bid = blockIdx.x;
  const int b = (bid & 7) * 16 + (bid >> 7);    // XCD-pinned batch (bijective)
  const int n0 = ((bid >> 3) & 15) * 128;

  const int w = tid >> 6;   // 8 waves: rows [n0+16w, n0+16w+16)
  const int l = tid & 63;
  const int lr = l & 15;
  const int g = l >> 4;

  const int ci = cell[b];
  const int n = n0 + w * 16 + lr;
  const float* rowp = mem + ((size_t)b * NN + n) * HH;
  float* orow = out + SCORES_OFF + ((size_t)b * NN + n) * HH;
  const float* avgp = avg + b * HH;
  const bool subst = (n == ci);
  const short* bsrc = Bimg + (size_t)b * KSTEPS * KIMG;

  f32x4 acc[13];
#pragma unroll
  for (int f = 0; f < 13; f++) acc[f] = (f32x4){0.f, 0.f, 0.f, 0.f};

  // ---- prologue: A(0) + B(0), cvt, drain ----
  float va[8];
  issueA(rowp, 8 * g, va);
#pragma unroll
  for (int it = 0; it < 4; it++) {
    int i = tid + it * 512;
    if (i < CH16) gload16(bsrc + (size_t)i * 8, &btS[0][i * 8]);
  }
  bf16x8 ahi, alo;
  cvtA(va, &ahi, &alo);     // counted vmcnt: waits A only (older than B gloads)
  __syncthreads();          // drains B(0)

  for (int ks = 0; ks < KSTEPS; ks++) {
    const int cur = ks & 1;
    const int kb_cur = ks * 32 + 8 * g;
    float vn[8];
    if (ks < KSTEPS - 1) {
      // issue next B into other buffer (read-complete since ks-1 barrier)
      const short* bs = bsrc + (size_t)(ks + 1) * KIMG;
#pragma unroll
      for (int it = 0; it < 4; it++) {
        int i = tid + it * 512;
        if (i < CH16) gload16(bs + (size_t)i * 8, &btS[cur ^ 1][i * 8]);
      }
      issueA(rowp, kb_cur + 32, vn);   // next A chunk -> regs (async)
    }
    storeA(va, kb_cur, orow, avgp, subst);  // new_mem for current (va resident)

    // ---- MFMA: 13 col-frags x 3 split products from btS[cur] ----
#pragma unroll
    for (int f = 0; f < 13; f++) {
      const short* bp = &btS[cur][(f * 16 + lr) * ROWSH + g * 8];
      bf16x8 bhi = *(const bf16x8*)bp;
      bf16x8 blo = *(const bf16x8*)(bp + 32);
      acc[f] = __builtin_amdgcn_mfma_f32_16x16x32_bf16(ahi, bhi, acc[f], 0, 0, 0);
      acc[f] = __builtin_amdgcn_mfma_f32_16x16x32_bf16(alo, bhi, acc[f], 0, 0, 0);
      acc[f] = __builtin_amdgcn_mfma_f32_16x16x32_bf16(ahi, blo, acc[f], 0, 0, 0);
    }

    if (ks < KSTEPS - 1) {
#pragma unroll
      for (int i = 0; i < 8; i++) va[i] = vn[i];
      cvtA(va, &ahi, &alo);   // vmcnt wait for next-A lands after MFMA phase
      __syncthreads();        // single barrier/kstep: drains gloads + stores
    }
  }

  epilogue(acc, b, n0, w, lr, g, bias, distW, cntW, W2, b2, ment, entc, dist, out);
}

// ---------------------------------------------------------------------------
extern "C" void kernel_launch(void* const* d_in, const int* in_sizes, int n_in,
                              void* d_out, int out_size, void* d_ws, size_t ws_size,
                              hipStream_t stream) {
  const float* q    = (const float*)d_in[0];
  const float* ment = (const float*)d_in[1];
  const float* mem  = (const float*)d_in[2];
  const int* entc   = (const int*)d_in[3];
  const int* dist   = (const int*)d_in[4];
  const int* lact   = (const int*)d_in[5];
  const int* cell   = (const int*)d_in[6];
  const float* W1   = (const float*)d_in[7];
  const float* b1   = (const float*)d_in[8];
  const float* W2   = (const float*)d_in[9];
  const float* b2   = (const float*)d_in[10];
  const float* dtab = (const float*)d_in[11];
  const float* ctab = (const float*)d_in[12];
  const float* atab = (const float*)d_in[13];
  float* out = (float*)d_out;

  // workspace: Bimg (38.3 MB shorts) | bias | distW | cntW | avg
  short* Bimg  = (short*)d_ws;
  float* fws   = (float*)(Bimg + BIMG_SHORTS);
  float* bias  = fws;
  float* distW = bias + BB * MM;
  float* cntW  = distW + 10 * MM;
  float* avg   = cntW + 10 * MM;

  k_prep2<<<1053, 320, 0, stream>>>(W1, b1, q, mem, dtab, ctab, atab, lact,
                                    entc, cell, distW, cntW, bias, avg, Bimg, out);
  k_main<<<2048, 512, 0, stream>>>(mem, Bimg, bias, distW, cntW, W2, b2, ment,
                                   entc, dist, cell, avg, out);
}